// Round 16
// baseline (38.438 us; speedup 1.0000x reference)
//
#include <hip/hip_runtime.h>
#include <math.h>

// RankingLoss = mean over rows of sum_{pairs: lab_a-lab_b > TOL} lsig(lg_a-lg_b)
//
// lsig(x) = -ln2*log2(1 + 2^{s_lo - s_hi}),  s = logit*log2e,  E = 2^s.
// Rows reordered bucket-major by label (bucket width = TOL). For j < C_i
// (C_i = start of bucket b_i-1) pair guaranteed valid, i = high:
//   tile core: t = E_j*invE_i; p = fma(t,p,p); v_log per 8; 512i x 256j tiles.
// Side pairs (C_i <= j < i): |ld|>TOL mask; (Ei+Ej) product + accS -= s_hi;
//   LDS-staged window; side blocks FIRST in grid.
// r16 changes: (1) tile order REVERSED (densest first -> no drain tail);
//   (2) rank_pre 512 threads (more waves hide barrier latency);
//   (3) reduction via deterministic int64 fixed-point atomicAdd into d_ws
//   (1 RMW/block, no fences); rank_final = 1-thread conversion.

#define NN 2048
#define BB 64
#define TOLF 0.01f
#define BLK 256
#define BLKP 512
#define NTILE 20                         // i-tiles of 512: offsets it*(it+1)
#define TILEBLKS (BB * NTILE)            // 1280
#define SIDEBLKS (BB * 8)                // 512
#define WGRID (TILEBLKS + SIDEBLKS)      // 1792
#define SWIN 448                         // side LDS window capacity
#define LOG2E 1.4426950408889634f
#define FIXSCALE 1048576.0               // 2^20

__device__ float2 g_labs[BB][NN];  // (label, s) bucket-major
__device__ float  g_Es[BB][NN];    // 2^s = e^logit
__device__ int    g_C[BB][NN];     // start of bucket b_i - 1

// ---------------- preprocess: bucket reorder via LDS, coalesced export ----------------
__global__ __launch_bounds__(BLKP) void rank_pre(const float* __restrict__ logits,
                                                 const float* __restrict__ labels,
                                                 unsigned long long* __restrict__ ws) {
    __shared__ float2 sls[NN];
    __shared__ float  sEv[NN];
    __shared__ int    sC[NN];
    __shared__ int    cnt[100], pref[101], offs[100];
    __shared__ int    wtot;
    const int row = blockIdx.x, tid = threadIdx.x;
    if (row == 0 && tid == 0) ws[0] = 0ULL;      // re-zero every launch (replay-safe)
    const float* lg = logits + (size_t)row * NN;
    const float* lb = labels + (size_t)row * NN;

    for (int x = tid; x < 100; x += BLKP) { cnt[x] = 0; offs[x] = 0; }
    __syncthreads();

    int   myb[4];
    float myla[4], mylg[4];
#pragma unroll
    for (int q = 0; q < 4; ++q) {
        int x = tid + q * BLKP;
        myla[q] = lb[x];
        mylg[q] = lg[x];
        myb[q]  = min(99, (int)(myla[q] * 100.0f));
        atomicAdd(&cnt[myb[q]], 1);
    }
    __syncthreads();
    {   // wave-parallel exclusive prefix over 100 counts (first 2 waves)
        int v = (tid < 100) ? cnt[tid] : 0;
        int x = v;
#pragma unroll
        for (int o = 1; o < 64; o <<= 1) {
            int y = __shfl_up(x, o);
            if ((tid & 63) >= o) x += y;
        }
        if (tid == 63) wtot = x;
        __syncthreads();
        if (tid >= 64 && tid < 128) x += wtot;
        if (tid < 101) pref[tid] = x - v;
    }
    __syncthreads();
#pragma unroll
    for (int q = 0; q < 4; ++q) {
        int b = myb[q];
        int p = pref[b] + atomicAdd(&offs[b], 1);
        float s = mylg[q] * LOG2E;
        sls[p] = make_float2(myla[q], s);
        sEv[p] = __builtin_amdgcn_exp2f(s);
        sC[p]  = (b >= 1) ? pref[b - 1] : 0;
    }
    __syncthreads();
    for (int x = tid; x < NN; x += BLKP) {
        g_labs[row][x] = sls[x];
        g_Es[row][x]   = sEv[x];
        g_C[row][x]    = sC[x];
    }
}

// ---------------- main work: side (LDS-staged, first) + tiles (dense-first) ----------------
__global__ __launch_bounds__(BLK) void rank_work(unsigned long long* __restrict__ ws) {
    const int bid = blockIdx.x;
    double blockv = 0.0;                 // this block's partial (log2 units)

    if (bid < SIDEBLKS) {
        // ---- side: bucket-distance <= 1 pairs, windows staged in LDS ----
        __shared__ float2 sLS[SWIN];
        __shared__ float  sE[SWIN];
        __shared__ int    sCs;
        __shared__ double sdw[4];
        const int row = bid >> 3;
        const int c0  = (bid & 7) << 8;
        const int tid = threadIdx.x;
        if (tid == 0) sCs = g_C[row][c0];
        __syncthreads();
        const int Cs  = sCs;
        const int len = c0 + 256 - Cs;
        for (int x = tid; x < len; x += BLK) {
            sLS[x] = g_labs[row][Cs + x];
            sE[x]  = g_Es[row][Cs + x];
        }
        __syncthreads();

        const int i    = c0 + tid;
        const int iloc = i - Cs;
        const float2 lsi = sLS[iloc];
        const float lai = lsi.x, si = lsi.y;
        const float Ei  = sE[iloc];
        const int wloc  = g_C[row][i] - Cs;

        float accL = 0.0f, accS = 0.0f;
        float p = 1.0f;
        int cnt8 = 0;
        for (int j = wloc; j < iloc; ++j) {
            float2 ls = sLS[j];
            float ld = lai - ls.x;
            bool valid = fabsf(ld) > TOLF;         // exact reference predicate
            float term = valid ? (Ei + sE[j]) : 1.0f;
            p *= term;
            if (++cnt8 == 8) { accL += __builtin_amdgcn_logf(p); p = 1.0f; cnt8 = 0; }
            float sh = (ld > 0.0f) ? si : ls.y;
            accS -= valid ? sh : 0.0f;
        }
        accL += __builtin_amdgcn_logf(p);

        double acc = (double)accL + (double)accS;
        for (int off = 32; off > 0; off >>= 1) acc += __shfl_down(acc, off);
        if ((tid & 63) == 0) sdw[tid >> 6] = acc;
        __syncthreads();
        if (tid == 0) blockv = sdw[0] + sdw[1] + sdw[2] + sdw[3];
    } else {
        // ---- tiles: mask-free core; order REVERSED so densest (it=3) run first ----
        __shared__ __align__(16) float swin[256];
        __shared__ float swave[4];
        const int tb = bid - SIDEBLKS;
        const int row = tb / NTILE;                // block-uniform
        const int t = (NTILE - 1) - (tb % NTILE);  // reversed: heavy first
        const int it = (t < 2) ? 0 : (t < 6) ? 1 : (t < 12) ? 2 : 3;
        const int jt = t - it * (it + 1);
        const int ibeg = it * 512, jbeg = jt * 256;

        float accL = 0.0f;
        const int Cmax = g_C[row][ibeg + 511];     // C monotone in position
        if (jbeg < Cmax) {
            for (int x = threadIdx.x; x < 64; x += BLK)
                ((float4*)swin)[x] = ((const float4*)&g_Es[row][jbeg])[x];
            __syncthreads();
            const int ia = ibeg + threadIdx.x;
            const int ib = ia + 256;
            const float invEa = __builtin_amdgcn_rcpf(g_Es[row][ia]);
            const float invEb = __builtin_amdgcn_rcpf(g_Es[row][ib]);
            int tripa = max(0, min(256, g_C[row][ia] - jbeg));
            int tripb = max(0, min(256, g_C[row][ib] - jbeg));   // >= tripa
            const int m16a = tripa & ~15;
            const int m16b = tripb & ~15;

            for (int jj = 0; jj < m16a; jj += 16) {
                const float4* q = (const float4*)&swin[jj];   // uniform: broadcast
                float4 w0 = q[0], w1 = q[1], w2 = q[2], w3 = q[3];
                float pa0 = 1.0f, pa1 = 1.0f, pb0 = 1.0f, pb1 = 1.0f;
                pa0 = fmaf(w0.x * invEa, pa0, pa0); pb0 = fmaf(w0.x * invEb, pb0, pb0);
                pa0 = fmaf(w0.y * invEa, pa0, pa0); pb0 = fmaf(w0.y * invEb, pb0, pb0);
                pa0 = fmaf(w0.z * invEa, pa0, pa0); pb0 = fmaf(w0.z * invEb, pb0, pb0);
                pa0 = fmaf(w0.w * invEa, pa0, pa0); pb0 = fmaf(w0.w * invEb, pb0, pb0);
                pa1 = fmaf(w1.x * invEa, pa1, pa1); pb1 = fmaf(w1.x * invEb, pb1, pb1);
                pa1 = fmaf(w1.y * invEa, pa1, pa1); pb1 = fmaf(w1.y * invEb, pb1, pb1);
                pa1 = fmaf(w1.z * invEa, pa1, pa1); pb1 = fmaf(w1.z * invEb, pb1, pb1);
                pa1 = fmaf(w1.w * invEa, pa1, pa1); pb1 = fmaf(w1.w * invEb, pb1, pb1);
                pa0 = fmaf(w2.x * invEa, pa0, pa0); pb0 = fmaf(w2.x * invEb, pb0, pb0);
                pa0 = fmaf(w2.y * invEa, pa0, pa0); pb0 = fmaf(w2.y * invEb, pb0, pb0);
                pa0 = fmaf(w2.z * invEa, pa0, pa0); pb0 = fmaf(w2.z * invEb, pb0, pb0);
                pa0 = fmaf(w2.w * invEa, pa0, pa0); pb0 = fmaf(w2.w * invEb, pb0, pb0);
                pa1 = fmaf(w3.x * invEa, pa1, pa1); pb1 = fmaf(w3.x * invEb, pb1, pb1);
                pa1 = fmaf(w3.y * invEa, pa1, pa1); pb1 = fmaf(w3.y * invEb, pb1, pb1);
                pa1 = fmaf(w3.z * invEa, pa1, pa1); pb1 = fmaf(w3.z * invEb, pb1, pb1);
                pa1 = fmaf(w3.w * invEa, pa1, pa1); pb1 = fmaf(w3.w * invEb, pb1, pb1);
                accL += __builtin_amdgcn_logf(pa0) + __builtin_amdgcn_logf(pa1)
                      + __builtin_amdgcn_logf(pb0) + __builtin_amdgcn_logf(pb1);
            }
            for (int jj = m16a; jj < m16b; jj += 16) {
                const float4* q = (const float4*)&swin[jj];
                float4 w0 = q[0], w1 = q[1], w2 = q[2], w3 = q[3];
                float pb0 = 1.0f, pb1 = 1.0f;
                pb0 = fmaf(w0.x * invEb, pb0, pb0);
                pb0 = fmaf(w0.y * invEb, pb0, pb0);
                pb0 = fmaf(w0.z * invEb, pb0, pb0);
                pb0 = fmaf(w0.w * invEb, pb0, pb0);
                pb1 = fmaf(w1.x * invEb, pb1, pb1);
                pb1 = fmaf(w1.y * invEb, pb1, pb1);
                pb1 = fmaf(w1.z * invEb, pb1, pb1);
                pb1 = fmaf(w1.w * invEb, pb1, pb1);
                pb0 = fmaf(w2.x * invEb, pb0, pb0);
                pb0 = fmaf(w2.y * invEb, pb0, pb0);
                pb0 = fmaf(w2.z * invEb, pb0, pb0);
                pb0 = fmaf(w2.w * invEb, pb0, pb0);
                pb1 = fmaf(w3.x * invEb, pb1, pb1);
                pb1 = fmaf(w3.y * invEb, pb1, pb1);
                pb1 = fmaf(w3.z * invEb, pb1, pb1);
                pb1 = fmaf(w3.w * invEb, pb1, pb1);
                accL += __builtin_amdgcn_logf(pb0) + __builtin_amdgcn_logf(pb1);
            }
            if (m16a < tripa) {
                float p0 = 1.0f, p1 = 1.0f;
#pragma unroll
                for (int u = 0; u < 8; ++u) {
                    float t0 = (m16a + u     < tripa) ? fmaf(swin[m16a + u],     invEa, 1.0f) : 1.0f;
                    float t1 = (m16a + 8 + u < tripa) ? fmaf(swin[m16a + 8 + u], invEa, 1.0f) : 1.0f;
                    p0 *= t0; p1 *= t1;
                }
                accL += __builtin_amdgcn_logf(p0) + __builtin_amdgcn_logf(p1);
            }
            if (m16b < tripb) {
                float p0 = 1.0f, p1 = 1.0f;
#pragma unroll
                for (int u = 0; u < 8; ++u) {
                    float t0 = (m16b + u     < tripb) ? fmaf(swin[m16b + u],     invEb, 1.0f) : 1.0f;
                    float t1 = (m16b + 8 + u < tripb) ? fmaf(swin[m16b + 8 + u], invEb, 1.0f) : 1.0f;
                    p0 *= t0; p1 *= t1;
                }
                accL += __builtin_amdgcn_logf(p0) + __builtin_amdgcn_logf(p1);
            }
        }
        float v = accL;
        for (int off = 32; off > 0; off >>= 1) v += __shfl_down(v, off);
        if ((threadIdx.x & 63) == 0) swave[threadIdx.x >> 6] = v;
        __syncthreads();
        if (threadIdx.x == 0)
            blockv = (double)(swave[0] + swave[1] + swave[2] + swave[3]);
    }

    if (threadIdx.x == 0) {
        // deterministic order-independent merge: int64 fixed-point
        long long q = llrint(blockv * FIXSCALE);
        atomicAdd(ws, (unsigned long long)q);     // wrap handles negatives
    }
}

__global__ __launch_bounds__(64) void rank_final(float* __restrict__ out,
                                                 const unsigned long long* __restrict__ ws) {
    if (threadIdx.x == 0) {
        long long tot = (long long)ws[0];
        out[0] = (float)((double)tot * (1.0 / FIXSCALE) *
                         (-0.6931471805599453 / (double)BB));
    }
}

extern "C" void kernel_launch(void* const* d_in, const int* in_sizes, int n_in,
                              void* d_out, int out_size, void* d_ws, size_t ws_size,
                              hipStream_t stream) {
    const float* logits = (const float*)d_in[0];
    const float* labels = (const float*)d_in[1];
    float* out = (float*)d_out;
    unsigned long long* ws = (unsigned long long*)d_ws;
    (void)in_sizes; (void)n_in; (void)out_size; (void)ws_size;

    rank_pre<<<BB, BLKP, 0, stream>>>(logits, labels, ws);
    rank_work<<<WGRID, BLK, 0, stream>>>(ws);
    rank_final<<<1, 64, 0, stream>>>(out, ws);
}

// Round 17
// 27.845 us; speedup vs baseline: 1.3804x; 1.3804x over previous
//
#include <hip/hip_runtime.h>
#include <math.h>

// RankingLoss = mean over rows of sum_{pairs: lab_a-lab_b > TOL} lsig(lg_a-lg_b)
//
// lsig(x) = -ln2*log2(1 + 2^{s_lo - s_hi}),  s = logit*log2e,  E = 2^s.
// Rows reordered bucket-major by label (bucket width = TOL). For j < C_i
// (C_i = start of bucket b_i-1) pair guaranteed valid, i = high:
//   tile core: t = E_j*invE_i; p = fma(t,p,p); v_log per 8; 512i x 256j tiles.
// Side pairs (C_i <= j < i): |ld|>TOL mask; (Ei+Ej) product + accS -= s_hi;
//   LDS-staged window; side blocks FIRST in grid.  (r15-proven, 27.1 us)
// r17: rank_pre rebuilt for parallelism (the ~12-15 us pig):
//   512 threads, per-wave histograms+scatter bases (8x less LDS-atomic
//   contention), float4-packed row data (lab,s,E,C) with single coalesced
//   dwordx4 export. rank_work/rank_final = r15 math, packed loads.

#define NN 2048
#define BB 64
#define TOLF 0.01f
#define BLK 256
#define BLKP 512
#define NTILE 20                         // i-tiles of 512: offsets it*(it+1)
#define TILEBLKS (BB * NTILE)            // 1280
#define SIDEBLKS (BB * 8)                // 512
#define WGRID (TILEBLKS + SIDEBLKS)      // 1792
#define SWIN 448                         // side LDS window capacity
#define LOG2E 1.4426950408889634f

__device__ float4 g_pack[BB][NN];  // (label, s, E=2^s, C-as-int-bits) bucket-major
__device__ float  g_part[TILEBLKS];
__device__ double g_partS[SIDEBLKS];

// ---------------- preprocess: bucket reorder, per-wave counters, packed export ----------------
__global__ __launch_bounds__(BLKP) void rank_pre(const float* __restrict__ logits,
                                                 const float* __restrict__ labels) {
    __shared__ float4 spk[NN];           // 32 KB packed row
    __shared__ int cnt[8][100];          // per-wave histograms
    __shared__ int offs[8][100];         // per-wave scatter bases (then counters)
    __shared__ int tot[100];
    __shared__ int pref[101];
    __shared__ int wtot;
    const int row = blockIdx.x, tid = threadIdx.x;
    const int wv = tid >> 6;
    const float* lg = logits + (size_t)row * NN;
    const float* lb = labels + (size_t)row * NN;

    for (int x = tid; x < 800; x += BLKP) ((int*)cnt)[x] = 0;
    __syncthreads();

    int   myb[4];
    float myla[4], mylg[4];
#pragma unroll
    for (int q = 0; q < 4; ++q) {
        int x = tid + q * BLKP;
        myla[q] = lb[x];
        mylg[q] = lg[x];
        myb[q]  = min(99, (int)(myla[q] * 100.0f));
        atomicAdd(&cnt[wv][myb[q]], 1);  // per-wave: ~8x less contention
    }
    __syncthreads();

    if (tid < 100) {                     // cross-wave bases + totals
        int run = 0;
#pragma unroll
        for (int w = 0; w < 8; ++w) { offs[w][tid] = run; run += cnt[w][tid]; }
        tot[tid] = run;
    }
    __syncthreads();

    {   // wave-parallel exclusive prefix over 100 totals (waves 0-1)
        int v = (tid < 100) ? tot[tid] : 0;
        int x = v;
#pragma unroll
        for (int o = 1; o < 64; o <<= 1) {
            int y = __shfl_up(x, o);
            if ((tid & 63) >= o) x += y;
        }
        if (tid == 63) wtot = x;
        __syncthreads();
        if (tid >= 64 && tid < 128) x += wtot;
        if (tid < 101) pref[tid] = x - v;
    }
    __syncthreads();

#pragma unroll
    for (int q = 0; q < 4; ++q) {
        int b = myb[q];
        int p = pref[b] + atomicAdd(&offs[wv][b], 1);   // base + within-wave rank
        float s = mylg[q] * LOG2E;
        spk[p] = make_float4(myla[q], s, __builtin_amdgcn_exp2f(s),
                             __int_as_float((b >= 1) ? pref[b - 1] : 0));
    }
    __syncthreads();

    for (int x = tid; x < NN; x += BLKP)     // coalesced dwordx4 export
        g_pack[row][x] = spk[x];
}

// ---------------- main work: side (LDS-staged, first) + tiles ----------------
__global__ __launch_bounds__(BLK) void rank_work() {
    const int bid = blockIdx.x;
    if (bid < SIDEBLKS) {
        // ---- side: bucket-distance <= 1 pairs, windows staged in LDS ----
        __shared__ float2 sLS[SWIN];
        __shared__ float  sE[SWIN];
        __shared__ int    sCs;
        __shared__ double sdw[4];
        const int row = bid >> 3;
        const int c0  = (bid & 7) << 8;
        const int tid = threadIdx.x;
        if (tid == 0) sCs = __float_as_int(g_pack[row][c0].w);
        __syncthreads();
        const int Cs  = sCs;
        const int len = c0 + 256 - Cs;
        for (int x = tid; x < len; x += BLK) {
            float4 v = g_pack[row][Cs + x];
            sLS[x] = make_float2(v.x, v.y);
            sE[x]  = v.z;
        }
        __syncthreads();

        const int i    = c0 + tid;
        const float4 pki = g_pack[row][i];
        const float lai = pki.x, si = pki.y;
        const float Ei  = pki.z;
        const int wloc  = __float_as_int(pki.w) - Cs;
        const int iloc  = i - Cs;

        float accL = 0.0f, accS = 0.0f;
        float p = 1.0f;
        int cnt8 = 0;
        for (int j = wloc; j < iloc; ++j) {
            float2 ls = sLS[j];
            float ld = lai - ls.x;
            bool valid = fabsf(ld) > TOLF;         // exact reference predicate
            float term = valid ? (Ei + sE[j]) : 1.0f;
            p *= term;
            if (++cnt8 == 8) { accL += __builtin_amdgcn_logf(p); p = 1.0f; cnt8 = 0; }
            float sh = (ld > 0.0f) ? si : ls.y;
            accS -= valid ? sh : 0.0f;
        }
        accL += __builtin_amdgcn_logf(p);

        double acc = (double)accL + (double)accS;
        for (int off = 32; off > 0; off >>= 1) acc += __shfl_down(acc, off);
        if ((tid & 63) == 0) sdw[tid >> 6] = acc;
        __syncthreads();
        if (tid == 0) g_partS[bid] = sdw[0] + sdw[1] + sdw[2] + sdw[3];
    } else {
        // ---- tiles: mask-free core (r13/r14/r15-proven) ----
        __shared__ __align__(16) float swin[256];
        __shared__ float swave[4];
        const int tb = bid - SIDEBLKS;
        const int row = tb / NTILE;                // block-uniform
        const int t = tb % NTILE;
        const int it = (t < 2) ? 0 : (t < 6) ? 1 : (t < 12) ? 2 : 3;
        const int jt = t - it * (it + 1);
        const int ibeg = it * 512, jbeg = jt * 256;

        float accL = 0.0f;
        const int Cmax = __float_as_int(g_pack[row][ibeg + 511].w);  // C monotone
        if (jbeg < Cmax) {
            swin[threadIdx.x] = g_pack[row][jbeg + threadIdx.x].z;
            __syncthreads();
            const int ia = ibeg + threadIdx.x;
            const int ib = ia + 256;
            const float4 pka = g_pack[row][ia];
            const float4 pkb = g_pack[row][ib];
            const float invEa = __builtin_amdgcn_rcpf(pka.z);
            const float invEb = __builtin_amdgcn_rcpf(pkb.z);
            int tripa = max(0, min(256, __float_as_int(pka.w) - jbeg));
            int tripb = max(0, min(256, __float_as_int(pkb.w) - jbeg));  // >= tripa
            const int m16a = tripa & ~15;
            const int m16b = tripb & ~15;

            for (int jj = 0; jj < m16a; jj += 16) {
                const float4* q = (const float4*)&swin[jj];   // uniform: broadcast
                float4 w0 = q[0], w1 = q[1], w2 = q[2], w3 = q[3];
                float pa0 = 1.0f, pa1 = 1.0f, pb0 = 1.0f, pb1 = 1.0f;
                pa0 = fmaf(w0.x * invEa, pa0, pa0); pb0 = fmaf(w0.x * invEb, pb0, pb0);
                pa0 = fmaf(w0.y * invEa, pa0, pa0); pb0 = fmaf(w0.y * invEb, pb0, pb0);
                pa0 = fmaf(w0.z * invEa, pa0, pa0); pb0 = fmaf(w0.z * invEb, pb0, pb0);
                pa0 = fmaf(w0.w * invEa, pa0, pa0); pb0 = fmaf(w0.w * invEb, pb0, pb0);
                pa1 = fmaf(w1.x * invEa, pa1, pa1); pb1 = fmaf(w1.x * invEb, pb1, pb1);
                pa1 = fmaf(w1.y * invEa, pa1, pa1); pb1 = fmaf(w1.y * invEb, pb1, pb1);
                pa1 = fmaf(w1.z * invEa, pa1, pa1); pb1 = fmaf(w1.z * invEb, pb1, pb1);
                pa1 = fmaf(w1.w * invEa, pa1, pa1); pb1 = fmaf(w1.w * invEb, pb1, pb1);
                pa0 = fmaf(w2.x * invEa, pa0, pa0); pb0 = fmaf(w2.x * invEb, pb0, pb0);
                pa0 = fmaf(w2.y * invEa, pa0, pa0); pb0 = fmaf(w2.y * invEb, pb0, pb0);
                pa0 = fmaf(w2.z * invEa, pa0, pa0); pb0 = fmaf(w2.z * invEb, pb0, pb0);
                pa0 = fmaf(w2.w * invEa, pa0, pa0); pb0 = fmaf(w2.w * invEb, pb0, pb0);
                pa1 = fmaf(w3.x * invEa, pa1, pa1); pb1 = fmaf(w3.x * invEb, pb1, pb1);
                pa1 = fmaf(w3.y * invEa, pa1, pa1); pb1 = fmaf(w3.y * invEb, pb1, pb1);
                pa1 = fmaf(w3.z * invEa, pa1, pa1); pb1 = fmaf(w3.z * invEb, pb1, pb1);
                pa1 = fmaf(w3.w * invEa, pa1, pa1); pb1 = fmaf(w3.w * invEb, pb1, pb1);
                accL += __builtin_amdgcn_logf(pa0) + __builtin_amdgcn_logf(pa1)
                      + __builtin_amdgcn_logf(pb0) + __builtin_amdgcn_logf(pb1);
            }
            for (int jj = m16a; jj < m16b; jj += 16) {
                const float4* q = (const float4*)&swin[jj];
                float4 w0 = q[0], w1 = q[1], w2 = q[2], w3 = q[3];
                float pb0 = 1.0f, pb1 = 1.0f;
                pb0 = fmaf(w0.x * invEb, pb0, pb0);
                pb0 = fmaf(w0.y * invEb, pb0, pb0);
                pb0 = fmaf(w0.z * invEb, pb0, pb0);
                pb0 = fmaf(w0.w * invEb, pb0, pb0);
                pb1 = fmaf(w1.x * invEb, pb1, pb1);
                pb1 = fmaf(w1.y * invEb, pb1, pb1);
                pb1 = fmaf(w1.z * invEb, pb1, pb1);
                pb1 = fmaf(w1.w * invEb, pb1, pb1);
                pb0 = fmaf(w2.x * invEb, pb0, pb0);
                pb0 = fmaf(w2.y * invEb, pb0, pb0);
                pb0 = fmaf(w2.z * invEb, pb0, pb0);
                pb0 = fmaf(w2.w * invEb, pb0, pb0);
                pb1 = fmaf(w3.x * invEb, pb1, pb1);
                pb1 = fmaf(w3.y * invEb, pb1, pb1);
                pb1 = fmaf(w3.z * invEb, pb1, pb1);
                pb1 = fmaf(w3.w * invEb, pb1, pb1);
                accL += __builtin_amdgcn_logf(pb0) + __builtin_amdgcn_logf(pb1);
            }
            if (m16a < tripa) {
                float p0 = 1.0f, p1 = 1.0f;
#pragma unroll
                for (int u = 0; u < 8; ++u) {
                    float t0 = (m16a + u     < tripa) ? fmaf(swin[m16a + u],     invEa, 1.0f) : 1.0f;
                    float t1 = (m16a + 8 + u < tripa) ? fmaf(swin[m16a + 8 + u], invEa, 1.0f) : 1.0f;
                    p0 *= t0; p1 *= t1;
                }
                accL += __builtin_amdgcn_logf(p0) + __builtin_amdgcn_logf(p1);
            }
            if (m16b < tripb) {
                float p0 = 1.0f, p1 = 1.0f;
#pragma unroll
                for (int u = 0; u < 8; ++u) {
                    float t0 = (m16b + u     < tripb) ? fmaf(swin[m16b + u],     invEb, 1.0f) : 1.0f;
                    float t1 = (m16b + 8 + u < tripb) ? fmaf(swin[m16b + 8 + u], invEb, 1.0f) : 1.0f;
                    p0 *= t0; p1 *= t1;
                }
                accL += __builtin_amdgcn_logf(p0) + __builtin_amdgcn_logf(p1);
            }
        }
        for (int off = 32; off > 0; off >>= 1) accL += __shfl_down(accL, off);
        if ((threadIdx.x & 63) == 0) swave[threadIdx.x >> 6] = accL;
        __syncthreads();
        if (threadIdx.x == 0)
            g_part[tb] = swave[0] + swave[1] + swave[2] + swave[3];
    }
}

__global__ __launch_bounds__(BLK) void rank_final(float* __restrict__ out) {
    double acc = 0.0;
    for (int idx = threadIdx.x; idx < TILEBLKS; idx += BLK) acc += (double)g_part[idx];
    for (int idx = threadIdx.x; idx < SIDEBLKS; idx += BLK) acc += g_partS[idx];
    for (int off = 32; off > 0; off >>= 1) acc += __shfl_down(acc, off);
    __shared__ double sw[4];
    if ((threadIdx.x & 63) == 0) sw[threadIdx.x >> 6] = acc;
    __syncthreads();
    if (threadIdx.x == 0)
        out[0] = (float)((sw[0] + sw[1] + sw[2] + sw[3]) *
                         (-0.6931471805599453 / (double)BB));
}

extern "C" void kernel_launch(void* const* d_in, const int* in_sizes, int n_in,
                              void* d_out, int out_size, void* d_ws, size_t ws_size,
                              hipStream_t stream) {
    const float* logits = (const float*)d_in[0];
    const float* labels = (const float*)d_in[1];
    float* out = (float*)d_out;
    (void)in_sizes; (void)n_in; (void)out_size; (void)d_ws; (void)ws_size;

    rank_pre<<<BB, BLKP, 0, stream>>>(logits, labels);
    rank_work<<<WGRID, BLK, 0, stream>>>();
    rank_final<<<1, BLK, 0, stream>>>(out);
}